// Round 9
// baseline (7900.047 us; speedup 1.0000x reference)
//
#include <hip/hip_runtime.h>
#include <math.h>

#define B_ 16
#define T_ 512
#define E_ 2048
#define H_ 1024
#define D_ 128
#define G_SCAN 64            // persistent workgroups for the scan (1 per CU, 64 <= 256 CUs)
#define ROWS_PER_WG 16       // H_/G_SCAN
#define N_REP 8              // one h-buffer replica per XCD
#define REP_STRIDE 2048      // u64 per replica (2 buffers x 1024 slots)
#define START_DELAY 2000     // initial phase alignment only (20 us)
#define T0_MAGIC 0x7F7F7F7Fu

typedef unsigned long long u64;

// ---------------- ws layout ----------------
// [256,   264)     : T0 handshake slot (u64 {magic, t0_low32}) -- zeroed each launch
// [4096,  135168)  : hbuf replicas: 8 x [2][H_] u64 {tag,valbits} -- zeroed (h0=0,tag=0)
// [135168,200704)  : hs[B_][H_] (float)
// [200704,+32MB)   : xW[B_*T_][H_] (float)

// ---- device-coherent 8B ops (sc0 sc1: bypass non-coherent caches to coherence point) ----
__device__ __forceinline__ void store_u64_cohere(u64* p, u64 v) {
    asm volatile("global_store_dwordx2 %0, %1, off sc0 sc1"
                 :: "v"(p), "v"(v) : "memory");
}
__device__ __forceinline__ u64 load_u64_cohere(const u64* p) {
    u64 r;
    asm volatile("global_load_dwordx2 %0, %1, off sc0 sc1\n\t"
                 "s_waitcnt vmcnt(0)"
                 : "=v"(r) : "v"(p) : "memory");
    return r;
}
// ---- 4 coherent 8B loads issued back-to-back, ONE waitcnt ----
__device__ __forceinline__ void load4_u64_cohere(
    const u64* p0, const u64* p1, const u64* p2, const u64* p3,
    u64& a, u64& b, u64& c, u64& d) {
    asm volatile("global_load_dwordx2 %0, %4, off sc0 sc1\n\t"
                 "global_load_dwordx2 %1, %5, off sc0 sc1\n\t"
                 "global_load_dwordx2 %2, %6, off sc0 sc1\n\t"
                 "global_load_dwordx2 %3, %7, off sc0 sc1\n\t"
                 "s_waitcnt vmcnt(0)"
                 : "=&v"(a), "=&v"(b), "=&v"(c), "=&v"(d)
                 : "v"(p0), "v"(p1), "v"(p2), "v"(p3)
                 : "memory");
}

// ---- wait until device-global realtime clock (100 MHz, XCD-coherent) reaches target ----
__device__ __forceinline__ void gate_wait(unsigned target) {
    for (;;) {
        unsigned now = (unsigned)__builtin_amdgcn_s_memrealtime();
        if ((int)(now - target) >= 0) break;   // signed diff: wrap-safe
        __builtin_amdgcn_s_sleep(1);
    }
}

// DPP butterfly add over a 16-lane row (VALU-rate, no LDS pipe).
template <int CTRL>
__device__ __forceinline__ float dpp_xadd(float v) {
    int vi = __float_as_int(v);
    int t  = __builtin_amdgcn_update_dpp(vi, vi, CTRL, 0xF, 0xF, true);
    return v + __int_as_float(t);
}

// fast tanh via v_exp_f32: tanh(x) = sign(x) * (1-e^{-2|x|})/(1+e^{-2|x|}); |err| ~1e-6
__device__ __forceinline__ float fast_tanh(float x) {
    float ax = fabsf(x);
    float e  = __expf(-2.0f * ax);
    float r  = __fdividef(1.0f - e, 1.0f + e);
    return copysignf(r, x);
}

// ================= Kernel 1: xW = x @ W_ih^T + (b_ih + b_hh) =================
__global__ __launch_bounds__(256) void gemm_xw(
    const float* __restrict__ x, const float* __restrict__ Wih,
    const float* __restrict__ bih, const float* __restrict__ bhh,
    float* __restrict__ xW)
{
    __shared__ float As[64][17];
    __shared__ float Bs[64][17];
    const int tid = threadIdx.x;
    const int bx = blockIdx.x;
    const int by = blockIdx.y;
    const int tx = tid & 15;
    const int ty = tid >> 4;
    const int lrow = tid >> 2;
    const int lcol = (tid & 3) * 4;

    const float* Ag = x   + (size_t)(by * 64 + lrow) * E_ + lcol;
    const float* Bg = Wih + (size_t)(bx * 64 + lrow) * E_ + lcol;

    float acc[4][4] = {};
    for (int kt = 0; kt < E_; kt += 16) {
        float4 av = *(const float4*)(Ag + kt);
        float4 bv = *(const float4*)(Bg + kt);
        As[lrow][lcol + 0] = av.x; As[lrow][lcol + 1] = av.y;
        As[lrow][lcol + 2] = av.z; As[lrow][lcol + 3] = av.w;
        Bs[lrow][lcol + 0] = bv.x; Bs[lrow][lcol + 1] = bv.y;
        Bs[lrow][lcol + 2] = bv.z; Bs[lrow][lcol + 3] = bv.w;
        __syncthreads();
#pragma unroll
        for (int kk = 0; kk < 16; ++kk) {
            float a0 = As[ty * 4 + 0][kk], a1 = As[ty * 4 + 1][kk];
            float a2 = As[ty * 4 + 2][kk], a3 = As[ty * 4 + 3][kk];
            float b0 = Bs[tx * 4 + 0][kk], b1 = Bs[tx * 4 + 1][kk];
            float b2 = Bs[tx * 4 + 2][kk], b3 = Bs[tx * 4 + 3][kk];
            acc[0][0] += a0 * b0; acc[0][1] += a0 * b1; acc[0][2] += a0 * b2; acc[0][3] += a0 * b3;
            acc[1][0] += a1 * b0; acc[1][1] += a1 * b1; acc[1][2] += a1 * b2; acc[1][3] += a1 * b3;
            acc[2][0] += a2 * b0; acc[2][1] += a2 * b1; acc[2][2] += a2 * b2; acc[2][3] += a2 * b3;
            acc[3][0] += a3 * b0; acc[3][1] += a3 * b1; acc[3][2] += a3 * b2; acc[3][3] += a3 * b3;
        }
        __syncthreads();
    }
#pragma unroll
    for (int i = 0; i < 4; ++i) {
        const int m = by * 64 + ty * 4 + i;
#pragma unroll
        for (int j = 0; j < 4; ++j) {
            const int n = bx * 64 + tx * 4 + j;
            xW[(size_t)m * H_ + n] = acc[i][j] + bih[n] + bhh[n];
        }
    }
}

// ================= Kernel 2: persistent sequential RNN scan =================
// Tagged-data protocol, PER-XCD REPLICATED: producers store each h value to 8
// replica regions (one per XCD); each consumer WG polls only the replica of its
// own XCD (HW_REG_XCC_ID) -> per-cache-line concurrency drops 64 -> 8 at L3.
// Replica choice affects only timing; all replicas carry identical tagged data,
// so correctness is placement-independent. 2-buffer WAR safety per replica:
// overwrite of buffer A at s+2 requires poll(s+2) on own replica -> all rows
// produced s+2 -> every wave completed poll(s) on buffer A (program order).
__global__ __launch_bounds__(256, 1) void rnn_scan(
    const float* __restrict__ Whh, const float* __restrict__ xW,
    const int* __restrict__ lengths,
    u64* __restrict__ tsync,   // T0 handshake slot
    u64* __restrict__ hbuf,    // 8 replicas x [2][H_] {tag<<32 | value_bits}
    float* __restrict__ hs)    // [B_][H_]
{
    __shared__ float hsh2[2][16 * 68];
    const int tid = threadIdx.x;
    const int wg  = blockIdx.x;
    const int r   = tid >> 4;     // 0..15
    const int sub = tid & 15;     // 0..15
    const int row = wg * ROWS_PER_WG + r;

    float wreg[64];
#pragma unroll
    for (int j = 0; j < 64; ++j)
        wreg[j] = Whh[(size_t)row * H_ + sub + 16 * j];

    // which XCD am I on? (wave-uniform SGPR; replica selector only)
    unsigned xcc;
    asm volatile("s_getreg_b32 %0, hwreg(HW_REG_XCC_ID)" : "=s"(xcc));
    xcc &= (N_REP - 1);
    const u64* myrep = hbuf + (size_t)xcc * REP_STRIDE;

    // ---- T0 handshake + single initial gate (align step-0 phase; no per-step gating)
    if (wg == 0 && tid == 0) {
        unsigned t0pub = (unsigned)__builtin_amdgcn_s_memrealtime() + START_DELAY;
        store_u64_cohere(tsync, ((u64)T0_MAGIC << 32) | (u64)t0pub);
    }
    {
        u64 v;
        do { v = load_u64_cohere(tsync); } while ((unsigned)(v >> 32) != T0_MAGIC);
        gate_wait((unsigned)v);
    }

    int s = 0, cur = 0;
    for (int b = 0; b < B_; ++b) {
        const int len = lengths[b];
        for (int t = 0; t < len; ++t) {
            // xW prefetch: issue early so it flies under the poll
            float xw = xW[(size_t)(b * T_ + t) * H_ + row];

            // ---- consume: poll 4 tagged slots of OWN replica until all carry tag s
            const u64* bin = myrep + (size_t)(s & 1) * H_;
            const unsigned want = (unsigned)s;
            u64 v0, v1, v2, v3;
            for (;;) {
                load4_u64_cohere(bin + tid, bin + tid + 256, bin + tid + 512, bin + tid + 768,
                                 v0, v1, v2, v3);
                if ((((unsigned)(v0 >> 32)) == want) & (((unsigned)(v1 >> 32)) == want) &
                    (((unsigned)(v2 >> 32)) == want) & (((unsigned)(v3 >> 32)) == want))
                    break;
            }

            // stage into current LDS buffer: perm(c)=sub*68 + r + 16k (2-way banks = free)
            float* wr = &hsh2[cur][sub * 68 + r];
            wr[0]  = __uint_as_float((unsigned)v0);
            wr[16] = __uint_as_float((unsigned)v1);
            wr[32] = __uint_as_float((unsigned)v2);
            wr[48] = __uint_as_float((unsigned)v3);
            __syncthreads();   // the per-step barrier

            // ---- compute: 16x float4 LDS reads, 64 FMA in 4 independent chains
            const float* hrow = &hsh2[cur][sub * 68];
            float p0 = 0.f, p1 = 0.f, p2 = 0.f, p3 = 0.f;
#pragma unroll
            for (int m = 0; m < 16; ++m) {
                float4 hv = *(const float4*)(hrow + 4 * m);
                p0 += wreg[4 * m + 0] * hv.x;
                p1 += wreg[4 * m + 1] * hv.y;
                p2 += wreg[4 * m + 2] * hv.z;
                p3 += wreg[4 * m + 3] * hv.w;
            }
            float p = (p0 + p1) + (p2 + p3);
            // DPP butterfly over the 16-lane group (VALU-rate; no LDS pipe)
            p = dpp_xadd<0xB1>(p);    // quad_perm [1,0,3,2]  (xor 1)
            p = dpp_xadd<0x4E>(p);    // quad_perm [2,3,0,1]  (xor 2)
            p = dpp_xadd<0x141>(p);   // row_half_mirror
            p = dpp_xadd<0x140>(p);   // row_mirror

            float v = fast_tanh(xw + p);
            // ---- produce: tagged 8B store to ALL replicas (fire-and-forget x8)
            if (sub == 0) {
                u64 pk = ((u64)(unsigned)(s + 1) << 32) | (u64)__float_as_uint(v);
                u64* pb = hbuf + (size_t)((s + 1) & 1) * H_ + row;
#pragma unroll
                for (int k = 0; k < N_REP; ++k)
                    store_u64_cohere(pb + (size_t)k * REP_STRIDE, pk);
                if (t == len - 1) hs[(size_t)b * H_ + row] = v;  // final h of this row
            }
            cur ^= 1;
            ++s;
        }
    }
}

// ================= Kernel 3: out = hs @ W_l1^T + b_l1  (16x128) =================
__global__ __launch_bounds__(128) void out_gemm(
    const float* __restrict__ hs, const float* __restrict__ Wl1,
    const float* __restrict__ bl1, float* __restrict__ out)
{
    __shared__ float hshared[H_];
    const int b = blockIdx.x;
    const int d = threadIdx.x;
    for (int i = d; i < H_ / 4; i += 128)
        ((float4*)hshared)[i] = ((const float4*)(hs + (size_t)b * H_))[i];
    __syncthreads();
    float acc = 0.f;
    const float* wrow = Wl1 + (size_t)d * H_;
    for (int h = 0; h < H_; h += 4) {
        float4 w = *(const float4*)(wrow + h);
        acc += w.x * hshared[h] + w.y * hshared[h + 1]
             + w.z * hshared[h + 2] + w.w * hshared[h + 3];
    }
    out[b * D_ + d] = acc + bl1[d];
}

extern "C" void kernel_launch(void* const* d_in, const int* in_sizes, int n_in,
                              void* d_out, int out_size, void* d_ws, size_t ws_size,
                              hipStream_t stream) {
    const float* x       = (const float*)d_in[0];
    const int*   lengths = (const int*)  d_in[1];
    const float* Wih     = (const float*)d_in[2];
    const float* Whh     = (const float*)d_in[3];
    const float* bih     = (const float*)d_in[4];
    const float* bhh     = (const float*)d_in[5];
    const float* Wl1     = (const float*)d_in[6];
    const float* bl1     = (const float*)d_in[7];
    float* out = (float*)d_out;

    char* ws = (char*)d_ws;
    u64*   tsync = (u64*)(ws + 256);      // T0 handshake
    u64*   hbuf  = (u64*)(ws + 4096);     // 8 replicas x 16 KB = 128 KB
    float* hs  = (float*)(ws + 135168);   // 64 KB
    float* xW  = (float*)(ws + 200704);   // 32 MB

    // zero tsync + all hbuf replicas (h0 = 0.0f, tag 0); ws re-poisoned every launch
    hipMemsetAsync(ws, 0, 200704, stream);

    dim3 g1(H_ / 64, (B_ * T_) / 64);   // (16, 128)
    gemm_xw<<<g1, 256, 0, stream>>>(x, Wih, bih, bhh, xW);

    rnn_scan<<<G_SCAN, 256, 0, stream>>>(Whh, xW, lengths, tsync, hbuf, hs);

    out_gemm<<<B_, D_, 0, stream>>>(hs, Wl1, bl1, out);
}

// Round 10
// 7159.434 us; speedup vs baseline: 1.1034x; 1.1034x over previous
//
#include <hip/hip_runtime.h>
#include <math.h>

#define B_ 16
#define T_ 512
#define E_ 2048
#define H_ 1024
#define D_ 128
#define G_SCAN 64            // scan WGs (1 per CU)
#define ROWS_PER_WG 16       // H_/G_SCAN
#define G_TOTAL 256          // scan + gemm WGs, all co-resident (capacity >= 2 blocks/CU)
#define N_JOBS 2048          // 128 m-tiles x 16 n-tiles
#define TICK_P 75            // vestigial per-step gate (r7-measured best)
#define START_DELAY 2000
#define T0_MAGIC 0x7F7F7F7Fu

typedef unsigned long long u64;
typedef unsigned int u32;
typedef __attribute__((ext_vector_type(4))) u32 v4u;

// ---------------- ws layout ----------------
// [256,  264)    : T0 handshake slot (u64 {magic,t0}) -- zeroed each launch
// [1024, 9216)   : cnt[128] m-tile counters, stride 16 u32 (64B/line) -- zeroed
// [16384,32768)  : hbuf2[2][H_] u64 {tag,val} -- zeroed (h0=0, tag=0)
// [32768,98304)  : hs[B_][H_] float (fully written by scan)
// [131072,+32MB) : xW[B_*T_][H_] float (tile-gated, no zeroing needed)

// ---- device-coherent ops (sc0 sc1 -> coherence point; stores write through) ----
__device__ __forceinline__ void store_u64_cohere(u64* p, u64 v) {
    asm volatile("global_store_dwordx2 %0, %1, off sc0 sc1" :: "v"(p), "v"(v) : "memory");
}
__device__ __forceinline__ void store_f32_cohere(float* p, float v) {
    asm volatile("global_store_dword %0, %1, off sc0 sc1" :: "v"(p), "v"(v) : "memory");
}
__device__ __forceinline__ u64 load_u64_cohere(const u64* p) {
    u64 r;
    asm volatile("global_load_dwordx2 %0, %1, off sc0 sc1\n\ts_waitcnt vmcnt(0)"
                 : "=v"(r) : "v"(p) : "memory");
    return r;
}
__device__ __forceinline__ u32 load_u32_cohere(const u32* p) {
    u32 r;
    asm volatile("global_load_dword %0, %1, off sc0 sc1\n\ts_waitcnt vmcnt(0)"
                 : "=v"(r) : "v"(p) : "memory");
    return r;
}
// ---- one poll packet: 2x dwordx4 (h slots 4tid..4tid+3) + this step's xW value ----
__device__ __forceinline__ void poll_h_xw(const u64* ph, const float* pxw,
                                          v4u& A, v4u& B, float& xw) {
    asm volatile(
        "global_load_dwordx4 %0, %3, off sc0 sc1\n\t"
        "global_load_dwordx4 %1, %3, off offset:16 sc0 sc1\n\t"
        "global_load_dword   %2, %4, off sc0 sc1\n\t"
        "s_waitcnt vmcnt(0)"
        : "=&v"(A), "=&v"(B), "=&v"(xw)
        : "v"(ph), "v"(pxw)
        : "memory");
}

__device__ __forceinline__ void gate_wait(unsigned target) {
    for (;;) {
        unsigned now = (unsigned)__builtin_amdgcn_s_memrealtime();
        if ((int)(now - target) >= 0) break;
        __builtin_amdgcn_s_sleep(1);
    }
}

template <int CTRL>
__device__ __forceinline__ float dpp_xadd(float v) {
    int vi = __float_as_int(v);
    int t  = __builtin_amdgcn_update_dpp(vi, vi, CTRL, 0xF, 0xF, true);
    return v + __int_as_float(t);
}

__device__ __forceinline__ float fast_tanh(float x) {
    float ax = fabsf(x);
    float e  = __expf(-2.0f * ax);
    float r  = __fdividef(1.0f - e, 1.0f + e);
    return copysignf(r, x);
}

// ---- one 64x64 GEMM tile job: xW[mt-tile][nt-tile], write-through + counter ----
__device__ __forceinline__ void gemm_tile(
    int mt, int nt, int tid,
    const float* __restrict__ x, const float* __restrict__ Wih,
    const float* __restrict__ bih, const float* __restrict__ bhh,
    float* xW, u32* cnt, float (*As)[17], float (*Bs)[17])
{
    const int tx = tid & 15, ty = tid >> 4;
    const int lrow = tid >> 2, lcol = (tid & 3) * 4;
    const float* Ag = x   + (size_t)(mt * 64 + lrow) * E_ + lcol;
    const float* Bg = Wih + (size_t)(nt * 64 + lrow) * E_ + lcol;

    float acc[4][4] = {};
    for (int kt = 0; kt < E_; kt += 16) {
        float4 av = *(const float4*)(Ag + kt);
        float4 bv = *(const float4*)(Bg + kt);
        As[lrow][lcol + 0] = av.x; As[lrow][lcol + 1] = av.y;
        As[lrow][lcol + 2] = av.z; As[lrow][lcol + 3] = av.w;
        Bs[lrow][lcol + 0] = bv.x; Bs[lrow][lcol + 1] = bv.y;
        Bs[lrow][lcol + 2] = bv.z; Bs[lrow][lcol + 3] = bv.w;
        __syncthreads();
#pragma unroll
        for (int kk = 0; kk < 16; ++kk) {
            float a0 = As[ty * 4 + 0][kk], a1 = As[ty * 4 + 1][kk];
            float a2 = As[ty * 4 + 2][kk], a3 = As[ty * 4 + 3][kk];
            float b0 = Bs[tx * 4 + 0][kk], b1 = Bs[tx * 4 + 1][kk];
            float b2 = Bs[tx * 4 + 2][kk], b3 = Bs[tx * 4 + 3][kk];
            acc[0][0] += a0 * b0; acc[0][1] += a0 * b1; acc[0][2] += a0 * b2; acc[0][3] += a0 * b3;
            acc[1][0] += a1 * b0; acc[1][1] += a1 * b1; acc[1][2] += a1 * b2; acc[1][3] += a1 * b3;
            acc[2][0] += a2 * b0; acc[2][1] += a2 * b1; acc[2][2] += a2 * b2; acc[2][3] += a2 * b3;
            acc[3][0] += a3 * b0; acc[3][1] += a3 * b1; acc[3][2] += a3 * b2; acc[3][3] += a3 * b3;
        }
        __syncthreads();
    }
#pragma unroll
    for (int i = 0; i < 4; ++i) {
        const int m = mt * 64 + ty * 4 + i;
#pragma unroll
        for (int j = 0; j < 4; ++j) {
            const int n = nt * 64 + tx * 4 + j;
            store_f32_cohere(xW + (size_t)m * H_ + n, acc[i][j] + bih[n] + bhh[n]);
        }
    }
    asm volatile("s_waitcnt vmcnt(0)" ::: "memory");  // own stores at coherence point
    __syncthreads();                                  // all threads' stores drained
    if (tid == 0) atomicAdd(cnt + mt * 16, 1u);       // device-scope publish
}

// ================= Fused kernel: WGs 0-63 scan, WGs 64-255 GEMM =================
__global__ __launch_bounds__(256, 1) void fused_scan_gemm(
    const float* __restrict__ x, const float* __restrict__ Wih,
    const float* __restrict__ bih, const float* __restrict__ bhh,
    const float* __restrict__ Whh, const int* __restrict__ lengths,
    u64* tsync, u32* cnt, u64* hbuf2, float* xW, float* hs)
{
    __shared__ float As[64][17];
    __shared__ float Bs[64][17];
    __shared__ float hsh2[2][16 * 68];
    const int tid = threadIdx.x;
    const int wg  = blockIdx.x;

    if (wg >= G_SCAN) {
        // ---------------- GEMM role: grid-stride over tile jobs, m-major ----------------
        for (int j = wg - G_SCAN; j < N_JOBS; j += (G_TOTAL - G_SCAN))
            gemm_tile(j >> 4, j & 15, tid, x, Wih, bih, bhh, xW, cnt, As, Bs);
        return;
    }

    // ---------------- scan role (round-7 transport, dwordx4 polls) ----------------
    const int r   = tid >> 4;
    const int sub = tid & 15;
    const int row = wg * ROWS_PER_WG + r;

    float wreg[64];
#pragma unroll
    for (int j = 0; j < 64; ++j)
        wreg[j] = Whh[(size_t)row * H_ + sub + 16 * j];

    // slot c = 4*tid+k lives at hsh2[cur][(c&15)*68 + (c>>4)] = stage_base + 68k
    const int stage_base = 4 * (tid & 3) * 68 + (tid >> 2);

    if (wg == 0 && tid == 0) {
        unsigned t0pub = (unsigned)__builtin_amdgcn_s_memrealtime() + START_DELAY;
        store_u64_cohere(tsync, ((u64)T0_MAGIC << 32) | (u64)t0pub);
    }
    unsigned t0;
    {
        u64 v;
        do { v = load_u64_cohere(tsync); } while ((unsigned)(v >> 32) != T0_MAGIC);
        t0 = (unsigned)v;
    }

    int s = 0, cur = 0, conf = -1;
    for (int b = 0; b < B_; ++b) {
        const int len = lengths[b];
        for (int t = 0; t < len; ++t) {
            const int m  = b * T_ + t;
            const int mt = m >> 6;
            if (mt > conf) {   // xW tile gate (16 n-jobs done?) -- rare: 128 total
                u32 c;
                do { c = load_u32_cohere(cnt + mt * 16); } while (c < 16u);
                conf = mt;
            }
            gate_wait(t0 + (unsigned)s * TICK_P);

            // ---- consume: poll slots 4tid..4tid+3 (2x dwordx4) + xW in one packet
            const u64*   ph  = hbuf2 + (size_t)(s & 1) * H_ + 4 * tid;
            const float* pxw = xW + (size_t)m * H_ + row;
            const u32 want = (u32)s;
            v4u A, Bv; float xw;
            for (;;) {
                poll_h_xw(ph, pxw, A, Bv, xw);
                if ((A.y == want) & (A.w == want) & (Bv.y == want) & (Bv.w == want))
                    break;
            }

            float* wrp = &hsh2[cur][stage_base];
            wrp[0]   = __uint_as_float(A.x);
            wrp[68]  = __uint_as_float(A.z);
            wrp[136] = __uint_as_float(Bv.x);
            wrp[204] = __uint_as_float(Bv.z);
            __syncthreads();   // the per-step barrier

            const float* hrow = &hsh2[cur][sub * 68];
            float p0 = 0.f, p1 = 0.f, p2 = 0.f, p3 = 0.f;
#pragma unroll
            for (int mm = 0; mm < 16; ++mm) {
                float4 hv = *(const float4*)(hrow + 4 * mm);
                p0 += wreg[4 * mm + 0] * hv.x;
                p1 += wreg[4 * mm + 1] * hv.y;
                p2 += wreg[4 * mm + 2] * hv.z;
                p3 += wreg[4 * mm + 3] * hv.w;
            }
            float p = (p0 + p1) + (p2 + p3);
            p = dpp_xadd<0xB1>(p);    // quad_perm xor1
            p = dpp_xadd<0x4E>(p);    // quad_perm xor2
            p = dpp_xadd<0x141>(p);   // row_half_mirror
            p = dpp_xadd<0x140>(p);   // row_mirror

            float v = fast_tanh(xw + p);
            if (sub == 0) {
                u64 pk = ((u64)(u32)(s + 1) << 32) | (u64)__float_as_uint(v);
                store_u64_cohere(hbuf2 + (size_t)((s + 1) & 1) * H_ + row, pk);
                if (t == len - 1) hs[(size_t)b * H_ + row] = v;
            }
            cur ^= 1;
            ++s;
        }
    }
}

// ================= out = hs @ W_l1^T + b_l1  (16x128) =================
__global__ __launch_bounds__(128) void out_gemm(
    const float* __restrict__ hs, const float* __restrict__ Wl1,
    const float* __restrict__ bl1, float* __restrict__ out)
{
    __shared__ float hshared[H_];
    const int b = blockIdx.x;
    const int d = threadIdx.x;
    for (int i = d; i < H_ / 4; i += 128)
        ((float4*)hshared)[i] = ((const float4*)(hs + (size_t)b * H_))[i];
    __syncthreads();
    float acc = 0.f;
    const float* wrow = Wl1 + (size_t)d * H_;
    for (int h = 0; h < H_; h += 4) {
        float4 w = *(const float4*)(wrow + h);
        acc += w.x * hshared[h] + w.y * hshared[h + 1]
             + w.z * hshared[h + 2] + w.w * hshared[h + 3];
    }
    out[b * D_ + d] = acc + bl1[d];
}

extern "C" void kernel_launch(void* const* d_in, const int* in_sizes, int n_in,
                              void* d_out, int out_size, void* d_ws, size_t ws_size,
                              hipStream_t stream) {
    const float* x       = (const float*)d_in[0];
    const int*   lengths = (const int*)  d_in[1];
    const float* Wih     = (const float*)d_in[2];
    const float* Whh     = (const float*)d_in[3];
    const float* bih     = (const float*)d_in[4];
    const float* bhh     = (const float*)d_in[5];
    const float* Wl1     = (const float*)d_in[6];
    const float* bl1     = (const float*)d_in[7];
    float* out = (float*)d_out;

    char* ws = (char*)d_ws;
    u64*   tsync = (u64*)(ws + 256);
    u32*   cnt   = (u32*)(ws + 1024);     // 128 tiles x 16-u32 stride = 8 KB
    u64*   hbuf2 = (u64*)(ws + 16384);    // 16 KB
    float* hs    = (float*)(ws + 32768);  // 64 KB
    float* xW    = (float*)(ws + 131072); // 32 MB

    // zero tsync + cnt + hbuf2 (h0=0, tag 0); ws re-poisoned 0xAA every launch
    hipMemsetAsync(ws, 0, 32768, stream);

    fused_scan_gemm<<<G_TOTAL, 256, 0, stream>>>(
        x, Wih, bih, bhh, Whh, lengths, tsync, cnt, hbuf2, xW, hs);

    out_gemm<<<B_, D_, 0, stream>>>(hs, Wl1, bl1, out);
}